// Round 11
// baseline (934.646 us; speedup 1.0000x reference)
//
#include <hip/hip_runtime.h>
#include <hip/hip_bf16.h>

constexpr int Nn  = 32768;   // total nodes
constexpr int Ej  = 294912;  // total edges
constexpr int Bg  = 256;     // graphs
constexpr int EPG = 1152;    // edges per graph
constexpr int QW2  = 868;    // fused logical cols: qkv 768 (bf16) | r8 32 | skip 64 | qb 4 (fp32)
constexpr int QWP2 = 880;    // Wcat row stride (fp32 cols, padded)
constexpr int RSF  = 496;    // qkvr row stride in floats: 1984 B = 31 * 64 B
constexpr int RSH  = 992;    // qkvr row stride in halfwords
// qkvr row: bytes [0,1536): 768 bf16 = q[0,256) k[256,512) v[512,768) (halfword idx)
//           floats [384,416): r8 | [416,480): skip | [480,484): qb' | pad to 496
constexpr int ASF  = 304;    // abuf row floats: agg[0,256) | t8[256,288) | s[288,292) | pad
constexpr int SP   = 132;    // S/Wmat fp32 LDS row stride (floats)
constexpr int QS   = 80;     // Q/K bf16 LDS row stride (halfwords)
constexpr int VS   = 136;    // Vt/Wbf bf16 LDS row stride (halfwords)

typedef __attribute__((ext_vector_type(8))) short short8;   // 8 bf16 = 4 VGPRs (MFMA A/B frag)
typedef __attribute__((ext_vector_type(4))) float f32x4;    // MFMA C/D frag

// monotone float<->uint encoding for atomicMax on floats
__device__ __forceinline__ unsigned encf(float f) {
  unsigned u = __float_as_uint(f);
  return (u & 0x80000000u) ? ~u : (u | 0x80000000u);
}
__device__ __forceinline__ float decf(unsigned u) {
  return (u & 0x80000000u) ? __uint_as_float(u & 0x7FFFFFFFu) : __uint_as_float(~u);
}
// fp32 -> bf16 bits, round-to-nearest-even
__device__ __forceinline__ unsigned short f2bf(float f) {
  unsigned u = __float_as_uint(f);
  u += 0x7FFFu + ((u >> 16) & 1u);
  return (unsigned short)(u >> 16);
}
// 64-lane sum via DPP. Result valid in lane 63.
__device__ __forceinline__ float wave_red_sum(float x) {
  x += __int_as_float(__builtin_amdgcn_update_dpp(0, __float_as_int(x), 0x111, 0xf, 0xf, true));
  x += __int_as_float(__builtin_amdgcn_update_dpp(0, __float_as_int(x), 0x112, 0xf, 0xf, true));
  x += __int_as_float(__builtin_amdgcn_update_dpp(0, __float_as_int(x), 0x114, 0xf, 0xf, true));
  x += __int_as_float(__builtin_amdgcn_update_dpp(0, __float_as_int(x), 0x118, 0xf, 0xf, true));
  x += __int_as_float(__builtin_amdgcn_update_dpp(0, __float_as_int(x), 0x142, 0xf, 0xf, true));
  x += __int_as_float(__builtin_amdgcn_update_dpp(0, __float_as_int(x), 0x143, 0xf, 0xf, true));
  return x;
}

// h[n,c] = sum_d x[n,d] * Wn[d,c] + bn[c]   (XD=16)
__global__ void k_node_enc(const float* __restrict__ x, const float* __restrict__ W,
                           const float* __restrict__ b, float* __restrict__ h) {
  int tid = blockIdx.x * 256 + threadIdx.x;  // Nn*64
  int n = tid >> 6, c = tid & 63;
  float acc = b[c];
#pragma unroll
  for (int d = 0; d < 16; ++d)
    acc += x[n * 16 + d] * W[d * 64 + c];
  h[tid] = acc;
}

// G[l][h][a][c] = sum_d W_edge[a,d]*We_l[d][h64+c];  bb[l][h][c] = be + b_edge@We
__global__ void k_prep2(const float* __restrict__ We, const float* __restrict__ be,
                        const float* __restrict__ W_edge, const float* __restrict__ b_edge,
                        float* __restrict__ G, float* __restrict__ bb) {
  int tid = blockIdx.x * 256 + threadIdx.x;  // 8192 + 1024
  if (tid < 8192) {
    int l = tid >> 11, rem = tid & 2047;
    int hh = rem >> 9, a = (rem >> 6) & 7, c = rem & 63;
    float acc = 0.f;
#pragma unroll 8
    for (int d = 0; d < 64; ++d)
      acc += W_edge[a * 64 + d] * We[l * 16384 + d * 256 + hh * 64 + c];
    G[tid] = acc;
  } else if (tid < 9216) {
    int t = tid - 8192;
    int l = t >> 8, rem = t & 255;
    int hh = rem >> 6, c = rem & 63;
    float acc = be[l * 256 + hh * 64 + c];
#pragma unroll 8
    for (int d = 0; d < 64; ++d)
      acc += b_edge[d] * We[l * 16384 + d * 256 + hh * 64 + c];
    bb[t] = acc;
  }
}

// Light columns of Wcat/bcat: pure copies (+0.125 on q). Reads d_in only.
__global__ void k_prep_light(const float* __restrict__ Wq, const float* __restrict__ bq,
                             const float* __restrict__ Wk, const float* __restrict__ bk,
                             const float* __restrict__ Wv, const float* __restrict__ bv,
                             const float* __restrict__ Wskip, const float* __restrict__ bskip,
                             float* __restrict__ Wcat, float* __restrict__ bcat) {
  int tid = blockIdx.x * 256 + threadIdx.x;  // 4*64*QW2
  if (tid >= 4 * 64 * QW2) return;
  int l = tid / (64 * QW2);
  int rem = tid % (64 * QW2);
  int k = rem / QW2, col = rem % QW2;
  float w, bias;
  if (col < 256) {
    w = 0.125f * Wq[l * 16384 + k * 256 + col]; bias = 0.125f * bq[l * 256 + col];
  } else if (col < 512) {
    int j = col - 256; w = Wk[l * 16384 + k * 256 + j]; bias = bk[l * 256 + j];
  } else if (col < 768) {
    int j = col - 512; w = Wv[l * 16384 + k * 256 + j]; bias = bv[l * 256 + j];
  } else if (col >= 800 && col < 864) {
    int j = col - 800; w = Wskip[l * 4096 + k * 64 + j]; bias = bskip[l * 64 + j];
  } else {
    return;  // heavy cols [768,800) and [864,868) owned by k_prep_heavy
  }
  Wcat[(size_t)l * 64 * QWP2 + k * QWP2 + col] = w;
  if (k == 0) bcat[l * QW2 + col] = bias;
}

// Heavy columns: one WAVE per element. Reads d_in only.
__global__ void __launch_bounds__(256) k_prep_heavy(
    const float* __restrict__ Wq, const float* __restrict__ bq,
    const float* __restrict__ We, const float* __restrict__ be,
    const float* __restrict__ W_edge, const float* __restrict__ b_edge,
    float* __restrict__ Wcat, float* __restrict__ bcat) {
  int eid = blockIdx.x * 4 + (threadIdx.x >> 6);  // 2304 blocks * 4 waves
  int lane = threadIdx.x & 63;
  int l = eid / 2304;
  int rem = eid % 2304;
  int k = rem / 36, j = rem % 36;
  int hh, col;
  float inner;
  const float* We_l = We + l * 16384;
  if (j < 32) {
    hh = j >> 3;
    int a = j & 7;
    col = 768 + j;
    float s = 0.f;
#pragma unroll 8
    for (int d = 0; d < 64; ++d)
      s += We_l[d * 256 + hh * 64 + lane] * W_edge[a * 64 + d];
    inner = s;
  } else {
    hh = j - 32;
    col = 864 + hh;
    float s = be[l * 256 + hh * 64 + lane];
#pragma unroll 8
    for (int d = 0; d < 64; ++d)
      s += b_edge[d] * We_l[d * 256 + hh * 64 + lane];
    inner = s;
  }
  float w = Wq[l * 16384 + k * 256 + hh * 64 + lane] * inner;
  float b2 = bq[l * 256 + hh * 64 + lane] * inner;
  float sw = wave_red_sum(w);
  float sb = wave_red_sum(b2);
  if (lane == 63) {
    Wcat[(size_t)l * 64 * QWP2 + k * QWP2 + col] = 0.125f * sw;
    if (k == 0) bcat[l * QW2 + col] = 0.125f * sb;
  }
}

// Fused node GEMM with mixed-precision epilogue: cols [0,768) stored bf16, rest fp32.
__global__ void __launch_bounds__(256) k_qkv(const float* __restrict__ h,
                                             const float* __restrict__ Wcat_l,
                                             const float* __restrict__ bcat_l,
                                             float* __restrict__ out) {
  __shared__ float hL[16 * 64];
  int tid = threadIdx.x;
  int n0 = blockIdx.y * 16;
  {
    int n = tid >> 4, c4 = tid & 15;
    *(float4*)&hL[n * 64 + c4 * 4] = *(const float4*)&h[(size_t)(n0 + n) * 64 + c4 * 4];
  }
  __syncthreads();
  int jg = tid & 63, ng = tid >> 6;
  int j4 = blockIdx.x * 256 + jg * 4;
  if (j4 >= QW2) return;
  float4 acc[4] = {{0,0,0,0},{0,0,0,0},{0,0,0,0},{0,0,0,0}};
#pragma unroll
  for (int c4 = 0; c4 < 16; ++c4) {
    float4 h0 = *(const float4*)&hL[(ng * 4 + 0) * 64 + c4 * 4];
    float4 h1 = *(const float4*)&hL[(ng * 4 + 1) * 64 + c4 * 4];
    float4 h2 = *(const float4*)&hL[(ng * 4 + 2) * 64 + c4 * 4];
    float4 h3 = *(const float4*)&hL[(ng * 4 + 3) * 64 + c4 * 4];
    const float* hv0 = (const float*)&h0;
    const float* hv1 = (const float*)&h1;
    const float* hv2 = (const float*)&h2;
    const float* hv3 = (const float*)&h3;
#pragma unroll
    for (int cc = 0; cc < 4; ++cc) {
      float4 w = *(const float4*)&Wcat_l[(size_t)(c4 * 4 + cc) * QWP2 + j4];
      acc[0].x += hv0[cc] * w.x; acc[0].y += hv0[cc] * w.y; acc[0].z += hv0[cc] * w.z; acc[0].w += hv0[cc] * w.w;
      acc[1].x += hv1[cc] * w.x; acc[1].y += hv1[cc] * w.y; acc[1].z += hv1[cc] * w.z; acc[1].w += hv1[cc] * w.w;
      acc[2].x += hv2[cc] * w.x; acc[2].y += hv2[cc] * w.y; acc[2].z += hv2[cc] * w.z; acc[2].w += hv2[cc] * w.w;
      acc[3].x += hv3[cc] * w.x; acc[3].y += hv3[cc] * w.y; acc[3].z += hv3[cc] * w.z; acc[3].w += hv3[cc] * w.w;
    }
  }
  float4 bb = *(const float4*)&bcat_l[j4];
#pragma unroll
  for (int i = 0; i < 4; ++i) {
    acc[i].x += bb.x; acc[i].y += bb.y; acc[i].z += bb.z; acc[i].w += bb.w;
  }
  if (j4 < 768) {
    unsigned short* outH = (unsigned short*)out;
#pragma unroll
    for (int i = 0; i < 4; ++i) {
      uint2 u;
      u.x = f2bf(acc[i].x) | ((unsigned)f2bf(acc[i].y) << 16);
      u.y = f2bf(acc[i].z) | ((unsigned)f2bf(acc[i].w) << 16);
      *(uint2*)&outH[(size_t)(n0 + ng * 4 + i) * RSH + j4] = u;
    }
  } else {
#pragma unroll
    for (int i = 0; i < 4; ++i)
      *(float4*)&out[(size_t)(n0 + ng * 4 + i) * RSF + 384 + (j4 - 768)] = acc[i];
  }
}

// MFMA dense attention. Block = (g,h), 512 threads (8 waves), 128 KB LDS.
// Reads bf16 q/k/v + fp32 r8/qb from qkvr; writes agg/t8/s into abuf.
__global__ void __launch_bounds__(512) k_attn(const float* __restrict__ qkvr,
                                              float* __restrict__ abuf,
                                              const float* __restrict__ edge_attr,
                                              const int* __restrict__ ei) {
  __shared__ unsigned short Qu[128 * QS];   // Q bf16, stride 80
  __shared__ unsigned short KVu[128 * QS];  // P1: K (stride 80); P2+: Vt (64 x stride 136)
  __shared__ float S[128 * SP];             // fp32 scores -> Wmat fp32 -> (low) Wmat bf16
  __shared__ float alphaL[EPG];
  __shared__ int edL[EPG];                  // src | dst<<16
  __shared__ float r8L[128 * 8];
  __shared__ float t8L[128 * 9];            // stride 9: spread atomic banks
  __shared__ unsigned mL[128];
  __shared__ float sL[128], qbL[128];
  int g = blockIdx.x, h = blockIdx.y;
  int tid = threadIdx.x;
  int lane = tid & 63, m16 = lane & 15, quad = lane >> 4, wv = tid >> 6;
  const float* baseF = qkvr + (size_t)g * 128 * RSF;
  const unsigned short* baseH = (const unsigned short*)baseF;
  float* aF = abuf + (size_t)g * 128 * ASF;
  const float* eaG = edge_attr + (size_t)g * EPG * 8;

  // ---- P0: stage Q,K (bf16 direct); prefetch V into regs; r8, qb, edges; zero m/s/t8
  uint4 vpre[2];
#pragma unroll
  for (int s = 0; s < 2; ++s) {
    int idx = tid + s * 512;
    int n = idx >> 3, c8 = idx & 7;
    vpre[s] = *(const uint4*)&baseH[(size_t)n * RSH + 512 + h * 64 + c8 * 8];
  }
  for (int idx = tid; idx < 1024; idx += 512) {
    int n = idx >> 3, c8 = idx & 7;
    *(uint4*)&Qu[n * QS + c8 * 8] = *(const uint4*)&baseH[(size_t)n * RSH + h * 64 + c8 * 8];
    *(uint4*)&KVu[n * QS + c8 * 8] = *(const uint4*)&baseH[(size_t)n * RSH + 256 + h * 64 + c8 * 8];
  }
  for (int idx = tid; idx < 256; idx += 512) {
    int n = idx >> 1, pp = idx & 1;
    *(float4*)&r8L[n * 8 + pp * 4] = *(const float4*)&baseF[(size_t)n * RSF + 384 + h * 8 + pp * 4];
  }
  if (tid < 128) {
    qbL[tid] = baseF[(size_t)tid * RSF + 480 + h];
    mL[tid] = 0u;
    sL[tid] = 0.f;
  }
  for (int idx = tid; idx < EPG; idx += 512) {
    t8L[idx] = 0.f;
    int s = ei[g * EPG + idx] - g * 128;
    int d = ei[Ej + g * EPG + idx] - g * 128;
    edL[idx] = s | (d << 16);
  }
  __syncthreads();

  // ---- P1: S = Q@K^T.  Wave wv: dst-strip wv*16, all 8 src tiles. K=64 -> 2 mfma/tile.
  {
    int dst0 = wv * 16;
    const short8 a0 = *(const short8*)&Qu[(dst0 + m16) * QS + quad * 8];
    const short8 a1 = *(const short8*)&Qu[(dst0 + m16) * QS + 32 + quad * 8];
#pragma unroll
    for (int st = 0; st < 8; ++st) {
      int src0 = st * 16;
      const short8 b0 = *(const short8*)&KVu[(src0 + m16) * QS + quad * 8];
      const short8 b1 = *(const short8*)&KVu[(src0 + m16) * QS + 32 + quad * 8];
      f32x4 acc = {0.f, 0.f, 0.f, 0.f};
      acc = __builtin_amdgcn_mfma_f32_16x16x32_bf16(a0, b0, acc, 0, 0, 0);
      acc = __builtin_amdgcn_mfma_f32_16x16x32_bf16(a1, b1, acc, 0, 0, 0);
#pragma unroll
      for (int r = 0; r < 4; ++r)
        S[(dst0 + quad * 4 + r) * SP + src0 + m16] = acc[r];
    }
  }
  __syncthreads();

  // ---- P2: deposit prefetched Vt (transposed); per-edge alpha; segment max
#pragma unroll
  for (int s = 0; s < 2; ++s) {
    int idx = tid + s * 512;
    int n = idx >> 3, c8 = idx & 7;
    const unsigned short* pv = (const unsigned short*)&vpre[s];
#pragma unroll
    for (int j = 0; j < 8; ++j)
      KVu[(c8 * 8 + j) * VS + n] = pv[j];
  }
  for (int e = tid; e < EPG; e += 512) {
    int ed = edL[e];
    int src = ed & 0xffff, dst = ed >> 16;
    float4 ea0 = *(const float4*)(eaG + (size_t)e * 8);
    float4 ea1 = *(const float4*)(eaG + (size_t)e * 8 + 4);
    float4 r80 = *(const float4*)&r8L[dst * 8];
    float4 r81 = *(const float4*)&r8L[dst * 8 + 4];
    float a = S[dst * SP + src] + qbL[dst]
            + ea0.x * r80.x + ea0.y * r80.y + ea0.z * r80.z + ea0.w * r80.w
            + ea1.x * r81.x + ea1.y * r81.y + ea1.z * r81.z + ea1.w * r81.w;
    alphaL[e] = a;
    atomicMax(&mL[dst], encf(a));
  }
  __syncthreads();

  // ---- P3: zero S (whole buffer); exp + segment sum
  for (int idx = tid; idx < 128 * (SP / 4); idx += 512)
    *(float4*)&S[idx * 4] = make_float4(0.f, 0.f, 0.f, 0.f);
  for (int e = tid; e < EPG; e += 512) {
    int dst = edL[e] >> 16;
    float ex = expf(alphaL[e] - decf(mL[dst]));
    alphaL[e] = ex;
    atomicAdd(&sL[dst], ex);
  }
  __syncthreads();

  // ---- P4: scatter normalized weights into Wmat(fp32); accumulate t8 (stride 9)
  for (int e = tid; e < EPG; e += 512) {
    int ed = edL[e];
    int src = ed & 0xffff, dst = ed >> 16;
    float w = alphaL[e] / fmaxf(sL[dst], 1e-16f);
    atomicAdd(&S[dst * SP + src], w);
    float4 ea0 = *(const float4*)(eaG + (size_t)e * 8);
    float4 ea1 = *(const float4*)(eaG + (size_t)e * 8 + 4);
    float* t8 = &t8L[dst * 9];
    atomicAdd(t8 + 0, w * ea0.x); atomicAdd(t8 + 1, w * ea0.y);
    atomicAdd(t8 + 2, w * ea0.z); atomicAdd(t8 + 3, w * ea0.w);
    atomicAdd(t8 + 4, w * ea1.x); atomicAdd(t8 + 5, w * ea1.y);
    atomicAdd(t8 + 6, w * ea1.z); atomicAdd(t8 + 7, w * ea1.w);
  }
  __syncthreads();

  // ---- P4.5: repack Wmat fp32 -> bf16 in place (stride VS), regs + barrier
  {
    float vals[32];
    int i0 = tid * 32;
    int dst = i0 >> 7, src0 = i0 & 127;
#pragma unroll
    for (int i = 0; i < 32; ++i)
      vals[i] = S[dst * SP + src0 + i];
    __syncthreads();
    unsigned short* Wu = (unsigned short*)S;
#pragma unroll
    for (int g4 = 0; g4 < 4; ++g4) {
      uint4 u;
      u.x = f2bf(vals[g4 * 8 + 0]) | ((unsigned)f2bf(vals[g4 * 8 + 1]) << 16);
      u.y = f2bf(vals[g4 * 8 + 2]) | ((unsigned)f2bf(vals[g4 * 8 + 3]) << 16);
      u.z = f2bf(vals[g4 * 8 + 4]) | ((unsigned)f2bf(vals[g4 * 8 + 5]) << 16);
      u.w = f2bf(vals[g4 * 8 + 6]) | ((unsigned)f2bf(vals[g4 * 8 + 7]) << 16);
      *(uint4*)&Wu[dst * VS + src0 + g4 * 8] = u;
    }
  }
  __syncthreads();

  // ---- P5: agg = Wmat(128x128)@V(128x64) via MFMA -> abuf
  {
    const unsigned short* Wu = (const unsigned short*)S;
    int dst0 = wv * 16;
    short8 a[4];
#pragma unroll
    for (int ks = 0; ks < 4; ++ks)
      a[ks] = *(const short8*)&Wu[(dst0 + m16) * VS + ks * 32 + quad * 8];
#pragma unroll
    for (int ct = 0; ct < 4; ++ct) {
      int c0 = ct * 16;
      f32x4 acc = {0.f, 0.f, 0.f, 0.f};
#pragma unroll
      for (int ks = 0; ks < 4; ++ks) {
        const short8 b = *(const short8*)&KVu[(c0 + m16) * VS + ks * 32 + quad * 8];
        acc = __builtin_amdgcn_mfma_f32_16x16x32_bf16(a[ks], b, acc, 0, 0, 0);
      }
#pragma unroll
      for (int r = 0; r < 4; ++r)
        aF[(size_t)(dst0 + quad * 4 + r) * ASF + h * 64 + c0 + m16] = acc[r];
    }
  }
  // t8 + s writeback
  if (tid < 128) {
    float tmp[8];
#pragma unroll
    for (int j = 0; j < 8; ++j) tmp[j] = t8L[tid * 9 + j];
    *(float4*)(aF + (size_t)tid * ASF + 256 + h * 8) = make_float4(tmp[0], tmp[1], tmp[2], tmp[3]);
    *(float4*)(aF + (size_t)tid * ASF + 256 + h * 8 + 4) = make_float4(tmp[4], tmp[5], tmp[6], tmp[7]);
    aF[(size_t)tid * ASF + 288 + h] = sL[tid];
  }
}

// out[n,c] = 0.25*sum_h( agg + t8@G_h + (s>0)*bb_h ) + skip; stash virtual rows; h += out
__global__ void k_update(const float* __restrict__ qkvr, const float* __restrict__ abuf,
                         const float* __restrict__ G_l, const float* __restrict__ bb_l,
                         float* h, float* __restrict__ vemb, int layer) {
  int tid = blockIdx.x * 256 + threadIdx.x;  // Nn*64
  int n = tid >> 6, c = tid & 63;
  const float* rowA = abuf + (size_t)n * ASF;
  float acc = 0.f;
#pragma unroll
  for (int hh = 0; hh < 4; ++hh) {
    float sw = (rowA[288 + hh] > 0.f) ? 1.f : 0.f;
    float a = rowA[hh * 64 + c] + sw * bb_l[hh * 64 + c];
#pragma unroll
    for (int a8 = 0; a8 < 8; ++a8)
      a += rowA[256 + hh * 8 + a8] * G_l[(hh * 8 + a8) * 64 + c];
    acc += a;
  }
  float outv = acc * 0.25f + qkvr[(size_t)n * RSF + 416 + c];
  if ((n & 127) == 127)
    vemb[(n >> 7) * 256 + layer * 64 + c] = outv;
  h[tid] = outv + h[tid];
}

// pool = vemb @ W_down + b_down; out = sigmoid(pool @ W_out + b_out)
__global__ void k_head(const float* __restrict__ vemb, const float* __restrict__ Wd,
                       const float* __restrict__ bd, const float* __restrict__ Wo,
                       const float* __restrict__ bo, float* __restrict__ out) {
  int g = blockIdx.x;
  int c = threadIdx.x;  // 64 threads
  const float* vr = vemb + g * 256;
  float acc = bd[c];
#pragma unroll 16
  for (int j = 0; j < 256; ++j)
    acc += vr[j] * Wd[j * 64 + c];
  float p = acc * Wo[c];
#pragma unroll
  for (int off = 32; off; off >>= 1) p += __shfl_down(p, off);
  if (c == 0) {
    float logit = p + bo[0];
    out[g] = 1.f / (1.f + expf(-logit));
  }
}

extern "C" void kernel_launch(void* const* d_in, const int* in_sizes, int n_in,
                              void* d_out, int out_size, void* d_ws, size_t ws_size,
                              hipStream_t stream) {
  const float* x         = (const float*)d_in[0];
  const float* edge_attr = (const float*)d_in[1];
  const int*   ei        = (const int*)d_in[2];
  const float* W_node = (const float*)d_in[4];
  const float* b_node = (const float*)d_in[5];
  const float* W_edge = (const float*)d_in[6];
  const float* b_edge = (const float*)d_in[7];
  const float* Wq = (const float*)d_in[8];
  const float* bq = (const float*)d_in[9];
  const float* Wk = (const float*)d_in[10];
  const float* bk = (const float*)d_in[11];
  const float* Wv = (const float*)d_in[12];
  const float* bv = (const float*)d_in[13];
  const float* We = (const float*)d_in[14];
  const float* be = (const float*)d_in[15];
  const float* Wskip = (const float*)d_in[16];
  const float* bskip = (const float*)d_in[17];
  const float* W_down = (const float*)d_in[18];
  const float* b_down = (const float*)d_in[19];
  const float* W_out  = (const float*)d_in[20];
  const float* b_out  = (const float*)d_in[21];
  float* out = (float*)d_out;

  // workspace carve (fp32): ~114 MiB total
  float* p = (float*)d_ws;
  float* hbuf  = p; p += (size_t)Nn * 64;        //  8.4 MB
  float* qkvr  = p; p += (size_t)Nn * RSF;       // 65.0 MB
  float* abuf  = p; p += (size_t)Nn * ASF;       // 39.8 MB
  float* Wcat  = p; p += (size_t)4 * 64 * QWP2;
  float* bcat  = p; p += (size_t)4 * QW2;
  float* Gbuf  = p; p += (size_t)4 * 4 * 8 * 64;
  float* bbuf  = p; p += (size_t)4 * 4 * 64;
  float* vemb  = p; p += (size_t)Bg * 256;

  k_prep2<<<36, 256, 0, stream>>>(We, be, W_edge, b_edge, Gbuf, bbuf);
  k_prep_light<<<(4 * 64 * QW2 + 255) / 256, 256, 0, stream>>>(Wq, bq, Wk, bk, Wv, bv,
                                                               Wskip, bskip, Wcat, bcat);
  k_prep_heavy<<<2304, 256, 0, stream>>>(Wq, bq, We, be, W_edge, b_edge, Wcat, bcat);
  k_node_enc<<<Nn * 64 / 256, 256, 0, stream>>>(x, W_node, b_node, hbuf);

  for (int i = 0; i < 4; ++i) {
    k_qkv<<<dim3(4, Nn / 16), 256, 0, stream>>>(hbuf, Wcat + (size_t)i * 64 * QWP2,
                                                bcat + i * QW2, qkvr);
    k_attn<<<dim3(Bg, 4), 512, 0, stream>>>(qkvr, abuf, edge_attr, ei);
    k_update<<<Nn * 64 / 256, 256, 0, stream>>>(qkvr, abuf, Gbuf + i * 2048,
                                                bbuf + i * 256, hbuf, vemb, i);
  }
  k_head<<<Bg, 64, 0, stream>>>(vemb, W_down, b_down, W_out, b_out, out);
}

// Round 12
// 913.371 us; speedup vs baseline: 1.0233x; 1.0233x over previous
//
#include <hip/hip_runtime.h>
#include <hip/hip_bf16.h>

constexpr int Nn  = 32768;   // total nodes
constexpr int Ej  = 294912;  // total edges
constexpr int Bg  = 256;     // graphs
constexpr int EPG = 1152;    // edges per graph
constexpr int QW2  = 868;    // fused logical cols: qkv 768 (bf16) | r8 32 | skip 64 | qb 4 (fp32)
constexpr int QWP2 = 880;    // Wcat row stride (fp32 cols, padded)
constexpr int RSF  = 496;    // qkvr row stride in floats: 1984 B = 31 * 64 B
constexpr int RSH  = 992;    // qkvr row stride in halfwords
// qkvr row: halfwords [0,768): q[0,256) k[256,512) v[512,768)
//           floats [384,416): r8 | [416,480): skip | [480,484): qb' | pad to 496
constexpr int ASF  = 304;    // abuf row floats: agg[0,256) | t8[256,288) | s[288,292) | pad
constexpr int SP   = 132;    // S/Wmat fp32 LDS row stride (floats)
constexpr int QS   = 80;     // Q/K bf16 LDS row stride (halfwords)
constexpr int VS   = 136;    // Vt/Wbf bf16 LDS row stride (halfwords)

typedef __attribute__((ext_vector_type(8))) short short8;   // 8 bf16 = 4 VGPRs (MFMA A/B frag)
typedef __attribute__((ext_vector_type(4))) float f32x4;    // MFMA C/D frag

// monotone float<->uint encoding for atomicMax on floats
__device__ __forceinline__ unsigned encf(float f) {
  unsigned u = __float_as_uint(f);
  return (u & 0x80000000u) ? ~u : (u | 0x80000000u);
}
__device__ __forceinline__ float decf(unsigned u) {
  return (u & 0x80000000u) ? __uint_as_float(u & 0x7FFFFFFFu) : __uint_as_float(~u);
}
// fp32 -> bf16 bits, round-to-nearest-even
__device__ __forceinline__ unsigned short f2bf(float f) {
  unsigned u = __float_as_uint(f);
  u += 0x7FFFu + ((u >> 16) & 1u);
  return (unsigned short)(u >> 16);
}
// 64-lane sum via DPP. Result valid in lane 63.
__device__ __forceinline__ float wave_red_sum(float x) {
  x += __int_as_float(__builtin_amdgcn_update_dpp(0, __float_as_int(x), 0x111, 0xf, 0xf, true));
  x += __int_as_float(__builtin_amdgcn_update_dpp(0, __float_as_int(x), 0x112, 0xf, 0xf, true));
  x += __int_as_float(__builtin_amdgcn_update_dpp(0, __float_as_int(x), 0x114, 0xf, 0xf, true));
  x += __int_as_float(__builtin_amdgcn_update_dpp(0, __float_as_int(x), 0x118, 0xf, 0xf, true));
  x += __int_as_float(__builtin_amdgcn_update_dpp(0, __float_as_int(x), 0x142, 0xf, 0xf, true));
  x += __int_as_float(__builtin_amdgcn_update_dpp(0, __float_as_int(x), 0x143, 0xf, 0xf, true));
  return x;
}

// h[n,c] = sum_d x[n,d] * Wn[d,c] + bn[c]   (XD=16)
__global__ void k_node_enc(const float* __restrict__ x, const float* __restrict__ W,
                           const float* __restrict__ b, float* __restrict__ h) {
  int tid = blockIdx.x * 256 + threadIdx.x;  // Nn*64
  int n = tid >> 6, c = tid & 63;
  float acc = b[c];
#pragma unroll
  for (int d = 0; d < 16; ++d)
    acc += x[n * 16 + d] * W[d * 64 + c];
  h[tid] = acc;
}

// G[l][h][a][c] = sum_d W_edge[a,d]*We_l[d][h64+c];  bb[l][h][c] = be + b_edge@We
__global__ void k_prep2(const float* __restrict__ We, const float* __restrict__ be,
                        const float* __restrict__ W_edge, const float* __restrict__ b_edge,
                        float* __restrict__ G, float* __restrict__ bb) {
  int tid = blockIdx.x * 256 + threadIdx.x;  // 8192 + 1024
  if (tid < 8192) {
    int l = tid >> 11, rem = tid & 2047;
    int hh = rem >> 9, a = (rem >> 6) & 7, c = rem & 63;
    float acc = 0.f;
#pragma unroll 8
    for (int d = 0; d < 64; ++d)
      acc += W_edge[a * 64 + d] * We[l * 16384 + d * 256 + hh * 64 + c];
    G[tid] = acc;
  } else if (tid < 9216) {
    int t = tid - 8192;
    int l = t >> 8, rem = t & 255;
    int hh = rem >> 6, c = rem & 63;
    float acc = be[l * 256 + hh * 64 + c];
#pragma unroll 8
    for (int d = 0; d < 64; ++d)
      acc += b_edge[d] * We[l * 16384 + d * 256 + hh * 64 + c];
    bb[t] = acc;
  }
}

// Light columns of Wcat/bcat: pure copies (+0.125 on q). Reads d_in only.
__global__ void k_prep_light(const float* __restrict__ Wq, const float* __restrict__ bq,
                             const float* __restrict__ Wk, const float* __restrict__ bk,
                             const float* __restrict__ Wv, const float* __restrict__ bv,
                             const float* __restrict__ Wskip, const float* __restrict__ bskip,
                             float* __restrict__ Wcat, float* __restrict__ bcat) {
  int tid = blockIdx.x * 256 + threadIdx.x;  // 4*64*QW2
  if (tid >= 4 * 64 * QW2) return;
  int l = tid / (64 * QW2);
  int rem = tid % (64 * QW2);
  int k = rem / QW2, col = rem % QW2;
  float w, bias;
  if (col < 256) {
    w = 0.125f * Wq[l * 16384 + k * 256 + col]; bias = 0.125f * bq[l * 256 + col];
  } else if (col < 512) {
    int j = col - 256; w = Wk[l * 16384 + k * 256 + j]; bias = bk[l * 256 + j];
  } else if (col < 768) {
    int j = col - 512; w = Wv[l * 16384 + k * 256 + j]; bias = bv[l * 256 + j];
  } else if (col >= 800 && col < 864) {
    int j = col - 800; w = Wskip[l * 4096 + k * 64 + j]; bias = bskip[l * 64 + j];
  } else {
    return;  // heavy cols owned by k_prep_heavy
  }
  Wcat[(size_t)l * 64 * QWP2 + k * QWP2 + col] = w;
  if (k == 0) bcat[l * QW2 + col] = bias;
}

// Heavy columns: one WAVE per element. Reads d_in only.
__global__ void __launch_bounds__(256) k_prep_heavy(
    const float* __restrict__ Wq, const float* __restrict__ bq,
    const float* __restrict__ We, const float* __restrict__ be,
    const float* __restrict__ W_edge, const float* __restrict__ b_edge,
    float* __restrict__ Wcat, float* __restrict__ bcat) {
  int eid = blockIdx.x * 4 + (threadIdx.x >> 6);  // 2304 blocks * 4 waves
  int lane = threadIdx.x & 63;
  int l = eid / 2304;
  int rem = eid % 2304;
  int k = rem / 36, j = rem % 36;
  int hh, col;
  float inner;
  const float* We_l = We + l * 16384;
  if (j < 32) {
    hh = j >> 3;
    int a = j & 7;
    col = 768 + j;
    float s = 0.f;
#pragma unroll 8
    for (int d = 0; d < 64; ++d)
      s += We_l[d * 256 + hh * 64 + lane] * W_edge[a * 64 + d];
    inner = s;
  } else {
    hh = j - 32;
    col = 864 + hh;
    float s = be[l * 256 + hh * 64 + lane];
#pragma unroll 8
    for (int d = 0; d < 64; ++d)
      s += b_edge[d] * We_l[d * 256 + hh * 64 + lane];
    inner = s;
  }
  float w = Wq[l * 16384 + k * 256 + hh * 64 + lane] * inner;
  float b2 = bq[l * 256 + hh * 64 + lane] * inner;
  float sw = wave_red_sum(w);
  float sb = wave_red_sum(b2);
  if (lane == 63) {
    Wcat[(size_t)l * 64 * QWP2 + k * QWP2 + col] = 0.125f * sw;
    if (k == 0) bcat[l * QW2 + col] = 0.125f * sb;
  }
}

// Fused node GEMM with mixed-precision epilogue: cols [0,768) stored bf16, rest fp32.
__global__ void __launch_bounds__(256) k_qkv(const float* __restrict__ h,
                                             const float* __restrict__ Wcat_l,
                                             const float* __restrict__ bcat_l,
                                             float* __restrict__ out) {
  __shared__ float hL[16 * 64];
  int tid = threadIdx.x;
  int n0 = blockIdx.y * 16;
  {
    int n = tid >> 4, c4 = tid & 15;
    *(float4*)&hL[n * 64 + c4 * 4] = *(const float4*)&h[(size_t)(n0 + n) * 64 + c4 * 4];
  }
  __syncthreads();
  int jg = tid & 63, ng = tid >> 6;
  int j4 = blockIdx.x * 256 + jg * 4;
  if (j4 >= QW2) return;
  float4 acc[4] = {{0,0,0,0},{0,0,0,0},{0,0,0,0},{0,0,0,0}};
#pragma unroll
  for (int c4 = 0; c4 < 16; ++c4) {
    float4 h0 = *(const float4*)&hL[(ng * 4 + 0) * 64 + c4 * 4];
    float4 h1 = *(const float4*)&hL[(ng * 4 + 1) * 64 + c4 * 4];
    float4 h2 = *(const float4*)&hL[(ng * 4 + 2) * 64 + c4 * 4];
    float4 h3 = *(const float4*)&hL[(ng * 4 + 3) * 64 + c4 * 4];
    const float* hv0 = (const float*)&h0;
    const float* hv1 = (const float*)&h1;
    const float* hv2 = (const float*)&h2;
    const float* hv3 = (const float*)&h3;
#pragma unroll
    for (int cc = 0; cc < 4; ++cc) {
      float4 w = *(const float4*)&Wcat_l[(size_t)(c4 * 4 + cc) * QWP2 + j4];
      acc[0].x += hv0[cc] * w.x; acc[0].y += hv0[cc] * w.y; acc[0].z += hv0[cc] * w.z; acc[0].w += hv0[cc] * w.w;
      acc[1].x += hv1[cc] * w.x; acc[1].y += hv1[cc] * w.y; acc[1].z += hv1[cc] * w.z; acc[1].w += hv1[cc] * w.w;
      acc[2].x += hv2[cc] * w.x; acc[2].y += hv2[cc] * w.y; acc[2].z += hv2[cc] * w.z; acc[2].w += hv2[cc] * w.w;
      acc[3].x += hv3[cc] * w.x; acc[3].y += hv3[cc] * w.y; acc[3].z += hv3[cc] * w.z; acc[3].w += hv3[cc] * w.w;
    }
  }
  float4 bb = *(const float4*)&bcat_l[j4];
#pragma unroll
  for (int i = 0; i < 4; ++i) {
    acc[i].x += bb.x; acc[i].y += bb.y; acc[i].z += bb.z; acc[i].w += bb.w;
  }
  if (j4 < 768) {
    unsigned short* outH = (unsigned short*)out;
#pragma unroll
    for (int i = 0; i < 4; ++i) {
      uint2 u;
      u.x = f2bf(acc[i].x) | ((unsigned)f2bf(acc[i].y) << 16);
      u.y = f2bf(acc[i].z) | ((unsigned)f2bf(acc[i].w) << 16);
      *(uint2*)&outH[(size_t)(n0 + ng * 4 + i) * RSH + j4] = u;
    }
  } else {
#pragma unroll
    for (int i = 0; i < 4; ++i)
      *(float4*)&out[(size_t)(n0 + ng * 4 + i) * RSF + 384 + (j4 - 768)] = acc[i];
  }
}

// MFMA dense attention. Block = (g,h), 1024 threads (16 waves), 128 KB LDS, 1 block/CU.
__global__ void __launch_bounds__(1024, 4) k_attn(const float* __restrict__ qkvr,
                                                  float* __restrict__ abuf,
                                                  const float* __restrict__ edge_attr,
                                                  const int* __restrict__ ei) {
  __shared__ unsigned short Qu[128 * QS];   // Q bf16, stride 80
  __shared__ unsigned short KVu[128 * QS];  // P1: K (stride 80); P2+: Vt (64 x stride 136)
  __shared__ float S[128 * SP];             // fp32 scores -> Wmat fp32 -> (low) Wmat bf16
  __shared__ float alphaL[EPG];
  __shared__ int edL[EPG];                  // src | dst<<16
  __shared__ float r8L[128 * 8];
  __shared__ float t8L[128 * 9];            // stride 9: spread atomic banks
  __shared__ unsigned mL[128];
  __shared__ float sL[128], qbL[128];
  int g = blockIdx.x, h = blockIdx.y;
  int tid = threadIdx.x;
  int lane = tid & 63, m16 = lane & 15, quad = lane >> 4, wv = tid >> 6;
  const float* baseF = qkvr + (size_t)g * 128 * RSF;
  const unsigned short* baseH = (const unsigned short*)baseF;
  float* aF = abuf + (size_t)g * 128 * ASF;
  const float* eaG = edge_attr + (size_t)g * EPG * 8;

  // ---- P0: stage Q,K (bf16 direct); prefetch V into regs; r8, qb, edges; zero m/s/t8
  int n8 = tid >> 3, c8 = tid & 7;  // 1024 threads = 128 nodes x 8 chunks, exactly
  uint4 vpre = *(const uint4*)&baseH[(size_t)n8 * RSH + 512 + h * 64 + c8 * 8];
  *(uint4*)&Qu[n8 * QS + c8 * 8] = *(const uint4*)&baseH[(size_t)n8 * RSH + h * 64 + c8 * 8];
  *(uint4*)&KVu[n8 * QS + c8 * 8] = *(const uint4*)&baseH[(size_t)n8 * RSH + 256 + h * 64 + c8 * 8];
  if (tid < 256) {
    int n = tid >> 1, pp = tid & 1;
    *(float4*)&r8L[n * 8 + pp * 4] = *(const float4*)&baseF[(size_t)n * RSF + 384 + h * 8 + pp * 4];
  } else if (tid < 384) {
    int n = tid - 256;
    qbL[n] = baseF[(size_t)n * RSF + 480 + h];
    mL[n] = 0u;
    sL[n] = 0.f;
  }
  for (int idx = tid; idx < EPG; idx += 1024) {
    t8L[idx] = 0.f;  // EPG == 128*9 covers t8L exactly
    int s = ei[g * EPG + idx] - g * 128;
    int d = ei[Ej + g * EPG + idx] - g * 128;
    edL[idx] = s | (d << 16);
  }
  __syncthreads();

  // ---- P1: S = Q@K^T.  2 waves per dst strip; each does 4 src tiles (2 mfma each).
  {
    int strip = wv >> 1, halfw = wv & 1;
    int dst0 = strip * 16;
    const short8 a0 = *(const short8*)&Qu[(dst0 + m16) * QS + quad * 8];
    const short8 a1 = *(const short8*)&Qu[(dst0 + m16) * QS + 32 + quad * 8];
#pragma unroll
    for (int t = 0; t < 4; ++t) {
      int src0 = (halfw * 4 + t) * 16;
      const short8 b0 = *(const short8*)&KVu[(src0 + m16) * QS + quad * 8];
      const short8 b1 = *(const short8*)&KVu[(src0 + m16) * QS + 32 + quad * 8];
      f32x4 acc = {0.f, 0.f, 0.f, 0.f};
      acc = __builtin_amdgcn_mfma_f32_16x16x32_bf16(a0, b0, acc, 0, 0, 0);
      acc = __builtin_amdgcn_mfma_f32_16x16x32_bf16(a1, b1, acc, 0, 0, 0);
#pragma unroll
      for (int r = 0; r < 4; ++r)
        S[(dst0 + quad * 4 + r) * SP + src0 + m16] = acc[r];
    }
  }
  __syncthreads();

  // ---- P2: deposit prefetched Vt (transposed); per-edge alpha; segment max
  {
    const unsigned short* pv = (const unsigned short*)&vpre;
#pragma unroll
    for (int j = 0; j < 8; ++j)
      KVu[(c8 * 8 + j) * VS + n8] = pv[j];
  }
  for (int e = tid; e < EPG; e += 1024) {
    int ed = edL[e];
    int src = ed & 0xffff, dst = ed >> 16;
    float4 ea0 = *(const float4*)(eaG + (size_t)e * 8);
    float4 ea1 = *(const float4*)(eaG + (size_t)e * 8 + 4);
    float4 r80 = *(const float4*)&r8L[dst * 8];
    float4 r81 = *(const float4*)&r8L[dst * 8 + 4];
    float a = S[dst * SP + src] + qbL[dst]
            + ea0.x * r80.x + ea0.y * r80.y + ea0.z * r80.z + ea0.w * r80.w
            + ea1.x * r81.x + ea1.y * r81.y + ea1.z * r81.z + ea1.w * r81.w;
    alphaL[e] = a;
    atomicMax(&mL[dst], encf(a));
  }
  __syncthreads();

  // ---- P3: zero S (whole buffer); exp + segment sum
  for (int idx = tid; idx < 128 * (SP / 4); idx += 1024)
    *(float4*)&S[idx * 4] = make_float4(0.f, 0.f, 0.f, 0.f);
  for (int e = tid; e < EPG; e += 1024) {
    int dst = edL[e] >> 16;
    float ex = expf(alphaL[e] - decf(mL[dst]));
    alphaL[e] = ex;
    atomicAdd(&sL[dst], ex);
  }
  __syncthreads();

  // ---- P4: scatter normalized weights into Wmat(fp32); accumulate t8 (stride 9)
  for (int e = tid; e < EPG; e += 1024) {
    int ed = edL[e];
    int src = ed & 0xffff, dst = ed >> 16;
    float w = alphaL[e] / fmaxf(sL[dst], 1e-16f);
    atomicAdd(&S[dst * SP + src], w);
    float4 ea0 = *(const float4*)(eaG + (size_t)e * 8);
    float4 ea1 = *(const float4*)(eaG + (size_t)e * 8 + 4);
    float* t8 = &t8L[dst * 9];
    atomicAdd(t8 + 0, w * ea0.x); atomicAdd(t8 + 1, w * ea0.y);
    atomicAdd(t8 + 2, w * ea0.z); atomicAdd(t8 + 3, w * ea0.w);
    atomicAdd(t8 + 4, w * ea1.x); atomicAdd(t8 + 5, w * ea1.y);
    atomicAdd(t8 + 6, w * ea1.z); atomicAdd(t8 + 7, w * ea1.w);
  }
  __syncthreads();

  // ---- P4.5: repack Wmat fp32 -> bf16 in place (stride VS), regs + barrier
  {
    float vals[16];
    int i0 = tid * 16;
    int dst = i0 >> 7, src0 = i0 & 127;
#pragma unroll
    for (int i = 0; i < 16; ++i)
      vals[i] = S[dst * SP + src0 + i];
    __syncthreads();
    unsigned short* Wu = (unsigned short*)S;
#pragma unroll
    for (int g4 = 0; g4 < 2; ++g4) {
      uint4 u;
      u.x = f2bf(vals[g4 * 8 + 0]) | ((unsigned)f2bf(vals[g4 * 8 + 1]) << 16);
      u.y = f2bf(vals[g4 * 8 + 2]) | ((unsigned)f2bf(vals[g4 * 8 + 3]) << 16);
      u.z = f2bf(vals[g4 * 8 + 4]) | ((unsigned)f2bf(vals[g4 * 8 + 5]) << 16);
      u.w = f2bf(vals[g4 * 8 + 6]) | ((unsigned)f2bf(vals[g4 * 8 + 7]) << 16);
      *(uint4*)&Wu[dst * VS + src0 + g4 * 8] = u;
    }
  }
  __syncthreads();

  // ---- P5: agg = Wmat(128x128)@V(128x64) via MFMA -> abuf. 2 waves/strip, 2 c-tiles each.
  {
    const unsigned short* Wu = (const unsigned short*)S;
    int strip = wv >> 1, halfc = wv & 1;
    int dst0 = strip * 16;
    short8 a[4];
#pragma unroll
    for (int ks = 0; ks < 4; ++ks)
      a[ks] = *(const short8*)&Wu[(dst0 + m16) * VS + ks * 32 + quad * 8];
#pragma unroll
    for (int t = 0; t < 2; ++t) {
      int c0 = (halfc * 2 + t) * 16;
      f32x4 acc = {0.f, 0.f, 0.f, 0.f};
#pragma unroll
      for (int ks = 0; ks < 4; ++ks) {
        const short8 b = *(const short8*)&KVu[(c0 + m16) * VS + ks * 32 + quad * 8];
        acc = __builtin_amdgcn_mfma_f32_16x16x32_bf16(a[ks], b, acc, 0, 0, 0);
      }
#pragma unroll
      for (int r = 0; r < 4; ++r)
        aF[(size_t)(dst0 + quad * 4 + r) * ASF + h * 64 + c0 + m16] = acc[r];
    }
  }
  // t8 + s writeback
  if (tid < 128) {
    float tmp[8];
#pragma unroll
    for (int j = 0; j < 8; ++j) tmp[j] = t8L[tid * 9 + j];
    *(float4*)(aF + (size_t)tid * ASF + 256 + h * 8) = make_float4(tmp[0], tmp[1], tmp[2], tmp[3]);
    *(float4*)(aF + (size_t)tid * ASF + 256 + h * 8 + 4) = make_float4(tmp[4], tmp[5], tmp[6], tmp[7]);
    aF[(size_t)tid * ASF + 288 + h] = sL[tid];
  }
}

// out[n,c] = 0.25*sum_h( agg + t8@G_h + (s>0)*bb_h ) + skip; stash virtual rows; h += out
__global__ void k_update(const float* __restrict__ qkvr, const float* __restrict__ abuf,
                         const float* __restrict__ G_l, const float* __restrict__ bb_l,
                         float* h, float* __restrict__ vemb, int layer) {
  int tid = blockIdx.x * 256 + threadIdx.x;  // Nn*64
  int n = tid >> 6, c = tid & 63;
  const float* rowA = abuf + (size_t)n * ASF;
  float acc = 0.f;
#pragma unroll
  for (int hh = 0; hh < 4; ++hh) {
    float sw = (rowA[288 + hh] > 0.f) ? 1.f : 0.f;
    float a = rowA[hh * 64 + c] + sw * bb_l[hh * 64 + c];
#pragma unroll
    for (int a8 = 0; a8 < 8; ++a8)
      a += rowA[256 + hh * 8 + a8] * G_l[(hh * 8 + a8) * 64 + c];
    acc += a;
  }
  float outv = acc * 0.25f + qkvr[(size_t)n * RSF + 416 + c];
  if ((n & 127) == 127)
    vemb[(n >> 7) * 256 + layer * 64 + c] = outv;
  h[tid] = outv + h[tid];
}

// pool = vemb @ W_down + b_down; out = sigmoid(pool @ W_out + b_out)
__global__ void k_head(const float* __restrict__ vemb, const float* __restrict__ Wd,
                       const float* __restrict__ bd, const float* __restrict__ Wo,
                       const float* __restrict__ bo, float* __restrict__ out) {
  int g = blockIdx.x;
  int c = threadIdx.x;  // 64 threads
  const float* vr = vemb + g * 256;
  float acc = bd[c];
#pragma unroll 16
  for (int j = 0; j < 256; ++j)
    acc += vr[j] * Wd[j * 64 + c];
  float p = acc * Wo[c];
#pragma unroll
  for (int off = 32; off; off >>= 1) p += __shfl_down(p, off);
  if (c == 0) {
    float logit = p + bo[0];
    out[g] = 1.f / (1.f + expf(-logit));
  }
}

extern "C" void kernel_launch(void* const* d_in, const int* in_sizes, int n_in,
                              void* d_out, int out_size, void* d_ws, size_t ws_size,
                              hipStream_t stream) {
  const float* x         = (const float*)d_in[0];
  const float* edge_attr = (const float*)d_in[1];
  const int*   ei        = (const int*)d_in[2];
  const float* W_node = (const float*)d_in[4];
  const float* b_node = (const float*)d_in[5];
  const float* W_edge = (const float*)d_in[6];
  const float* b_edge = (const float*)d_in[7];
  const float* Wq = (const float*)d_in[8];
  const float* bq = (const float*)d_in[9];
  const float* Wk = (const float*)d_in[10];
  const float* bk = (const float*)d_in[11];
  const float* Wv = (const float*)d_in[12];
  const float* bv = (const float*)d_in[13];
  const float* We = (const float*)d_in[14];
  const float* be = (const float*)d_in[15];
  const float* Wskip = (const float*)d_in[16];
  const float* bskip = (const float*)d_in[17];
  const float* W_down = (const float*)d_in[18];
  const float* b_down = (const float*)d_in[19];
  const float* W_out  = (const float*)d_in[20];
  const float* b_out  = (const float*)d_in[21];
  float* out = (float*)d_out;

  // workspace carve (fp32): ~114 MiB total
  float* p = (float*)d_ws;
  float* hbuf  = p; p += (size_t)Nn * 64;        //  8.4 MB
  float* qkvr  = p; p += (size_t)Nn * RSF;       // 65.0 MB
  float* abuf  = p; p += (size_t)Nn * ASF;       // 39.8 MB
  float* Wcat  = p; p += (size_t)4 * 64 * QWP2;
  float* bcat  = p; p += (size_t)4 * QW2;
  float* Gbuf  = p; p += (size_t)4 * 4 * 8 * 64;
  float* bbuf  = p; p += (size_t)4 * 4 * 64;
  float* vemb  = p; p += (size_t)Bg * 256;

  k_prep2<<<36, 256, 0, stream>>>(We, be, W_edge, b_edge, Gbuf, bbuf);
  k_prep_light<<<(4 * 64 * QW2 + 255) / 256, 256, 0, stream>>>(Wq, bq, Wk, bk, Wv, bv,
                                                               Wskip, bskip, Wcat, bcat);
  k_prep_heavy<<<2304, 256, 0, stream>>>(Wq, bq, We, be, W_edge, b_edge, Wcat, bcat);
  k_node_enc<<<Nn * 64 / 256, 256, 0, stream>>>(x, W_node, b_node, hbuf);

  for (int i = 0; i < 4; ++i) {
    k_qkv<<<dim3(4, Nn / 16), 256, 0, stream>>>(hbuf, Wcat + (size_t)i * 64 * QWP2,
                                                bcat + i * QW2, qkvr);
    k_attn<<<dim3(Bg, 4), 1024, 0, stream>>>(qkvr, abuf, edge_attr, ei);
    k_update<<<Nn * 64 / 256, 256, 0, stream>>>(qkvr, abuf, Gbuf + i * 2048,
                                                bbuf + i * 256, hbuf, vemb, i);
  }
  k_head<<<Bg, 64, 0, stream>>>(vemb, W_down, b_down, W_out, b_out, out);
}

// Round 13
// 674.419 us; speedup vs baseline: 1.3859x; 1.3543x over previous
//
#include <hip/hip_runtime.h>
#include <hip/hip_bf16.h>

constexpr int Nn  = 32768;   // total nodes
constexpr int Ej  = 294912;  // total edges
constexpr int Bg  = 256;     // graphs
constexpr int EPG = 1152;    // edges per graph
constexpr int WC  = 208;     // padded fused-GEMM col count per head: q64|k64|v64|r8:8|qb1|pad7
constexpr int ASF = 304;     // abuf row floats: agg[0,256) | t8[256,288) | s[288,292) | pad
constexpr int SP  = 132;     // S/Wmat fp32 LDS row stride (floats)
constexpr int QS  = 80;      // Q/K/hB bf16 LDS row stride (halfwords)
constexpr int VS  = 136;     // Vt/Wbf bf16 LDS row stride (halfwords)

typedef __attribute__((ext_vector_type(8))) short short8;   // 8 bf16 = 4 VGPRs (MFMA A/B frag)
typedef __attribute__((ext_vector_type(4))) float f32x4;    // MFMA C/D frag

// monotone float<->uint encoding for atomicMax on floats
__device__ __forceinline__ unsigned encf(float f) {
  unsigned u = __float_as_uint(f);
  return (u & 0x80000000u) ? ~u : (u | 0x80000000u);
}
__device__ __forceinline__ float decf(unsigned u) {
  return (u & 0x80000000u) ? __uint_as_float(u & 0x7FFFFFFFu) : __uint_as_float(~u);
}
// fp32 -> bf16 bits, round-to-nearest-even
__device__ __forceinline__ unsigned short f2bf(float f) {
  unsigned u = __float_as_uint(f);
  u += 0x7FFFu + ((u >> 16) & 1u);
  return (unsigned short)(u >> 16);
}
// 64-lane sum via DPP. Result valid in lane 63.
__device__ __forceinline__ float wave_red_sum(float x) {
  x += __int_as_float(__builtin_amdgcn_update_dpp(0, __float_as_int(x), 0x111, 0xf, 0xf, true));
  x += __int_as_float(__builtin_amdgcn_update_dpp(0, __float_as_int(x), 0x112, 0xf, 0xf, true));
  x += __int_as_float(__builtin_amdgcn_update_dpp(0, __float_as_int(x), 0x114, 0xf, 0xf, true));
  x += __int_as_float(__builtin_amdgcn_update_dpp(0, __float_as_int(x), 0x118, 0xf, 0xf, true));
  x += __int_as_float(__builtin_amdgcn_update_dpp(0, __float_as_int(x), 0x142, 0xf, 0xf, true));
  x += __int_as_float(__builtin_amdgcn_update_dpp(0, __float_as_int(x), 0x143, 0xf, 0xf, true));
  return x;
}

// h[n,c] = sum_d x[n,d] * Wn[d,c] + bn[c]   (XD=16)
__global__ void k_node_enc(const float* __restrict__ x, const float* __restrict__ W,
                           const float* __restrict__ b, float* __restrict__ h) {
  int tid = blockIdx.x * 256 + threadIdx.x;  // Nn*64
  int n = tid >> 6, c = tid & 63;
  float acc = b[c];
#pragma unroll
  for (int d = 0; d < 16; ++d)
    acc += x[n * 16 + d] * W[d * 64 + c];
  h[tid] = acc;
}

// G[l][h][a][c] = sum_d W_edge[a,d]*We_l[d][h64+c];  bb[l][h][c] = be + b_edge@We
__global__ void k_prep2(const float* __restrict__ We, const float* __restrict__ be,
                        const float* __restrict__ W_edge, const float* __restrict__ b_edge,
                        float* __restrict__ G, float* __restrict__ bb) {
  int tid = blockIdx.x * 256 + threadIdx.x;  // 8192 + 1024
  if (tid < 8192) {
    int l = tid >> 11, rem = tid & 2047;
    int hh = rem >> 9, a = (rem >> 6) & 7, c = rem & 63;
    float acc = 0.f;
#pragma unroll 8
    for (int d = 0; d < 64; ++d)
      acc += W_edge[a * 64 + d] * We[l * 16384 + d * 256 + hh * 64 + c];
    G[tid] = acc;
  } else if (tid < 9216) {
    int t = tid - 8192;
    int l = t >> 8, rem = t & 255;
    int hh = rem >> 6, c = rem & 63;
    float acc = be[l * 256 + hh * 64 + c];
#pragma unroll 8
    for (int d = 0; d < 64; ++d)
      acc += b_edge[d] * We[l * 16384 + d * 256 + hh * 64 + c];
    bb[t] = acc;
  }
}

// Light cols of WcatT (bf16, [l][h][col][k]) + bcatT (fp32). Reads d_in only.
// col<64: q (x0.125) | <128: k | <192: v | [192,201): heavy kernel | >=201: zero pad.
__global__ void k_prepT_light(const float* __restrict__ Wq, const float* __restrict__ bq,
                              const float* __restrict__ Wk, const float* __restrict__ bk,
                              const float* __restrict__ Wv, const float* __restrict__ bv,
                              unsigned short* __restrict__ WcatT, float* __restrict__ bcatT) {
  int tid = blockIdx.x * 256 + threadIdx.x;  // 4*4*WC*64
  if (tid >= 4 * 4 * WC * 64) return;
  int kk = tid & 63;
  int rest = tid >> 6;
  int col = rest % WC;
  int lh = rest / WC;
  int h = lh & 3, l = lh >> 2;
  float w, bias;
  if (col < 64) {
    w = 0.125f * Wq[l * 16384 + kk * 256 + h * 64 + col];
    bias = 0.125f * bq[l * 256 + h * 64 + col];
  } else if (col < 128) {
    int j = col - 64;
    w = Wk[l * 16384 + kk * 256 + h * 64 + j];
    bias = bk[l * 256 + h * 64 + j];
  } else if (col < 192) {
    int j = col - 128;
    w = Wv[l * 16384 + kk * 256 + h * 64 + j];
    bias = bv[l * 256 + h * 64 + j];
  } else if (col < 201) {
    return;  // heavy
  } else {
    w = 0.f; bias = 0.f;
  }
  WcatT[(size_t)(lh * WC + col) * 64 + kk] = f2bf(w);
  if (kk == 0) bcatT[lh * WC + col] = bias;
}

// Heavy cols (r8, qb'): one WAVE per element. Reads d_in only.
__global__ void __launch_bounds__(256) k_prepT_heavy(
    const float* __restrict__ Wq, const float* __restrict__ bq,
    const float* __restrict__ We, const float* __restrict__ be,
    const float* __restrict__ W_edge, const float* __restrict__ b_edge,
    unsigned short* __restrict__ WcatT, float* __restrict__ bcatT) {
  int eid = blockIdx.x * 4 + (threadIdx.x >> 6);  // 2304 blocks * 4 waves = 4*64*36
  int lane = threadIdx.x & 63;
  int l = eid / 2304;
  int rem = eid % 2304;
  int kk = rem / 36, j = rem % 36;
  int hh, col;
  float inner;
  const float* We_l = We + l * 16384;
  if (j < 32) {
    hh = j >> 3;
    int a = j & 7;
    col = 192 + a;
    float s = 0.f;
#pragma unroll 8
    for (int d = 0; d < 64; ++d)
      s += We_l[d * 256 + hh * 64 + lane] * W_edge[a * 64 + d];
    inner = s;
  } else {
    hh = j - 32;
    col = 200;
    float s = be[l * 256 + hh * 64 + lane];
#pragma unroll 8
    for (int d = 0; d < 64; ++d)
      s += b_edge[d] * We_l[d * 256 + hh * 64 + lane];
    inner = s;
  }
  float w = Wq[l * 16384 + kk * 256 + hh * 64 + lane] * inner;
  float b2 = bq[l * 256 + hh * 64 + lane] * inner;
  float sw = wave_red_sum(w);
  float sb = wave_red_sum(b2);
  if (lane == 63) {
    int lh = l * 4 + hh;
    WcatT[(size_t)(lh * WC + col) * 64 + kk] = f2bf(0.125f * sw);
    if (kk == 0) bcatT[lh * WC + col] = 0.125f * sb;
  }
}

// Fused QKV-GEMM + MFMA dense attention. Block = (g,h), 1024 threads, 128 KB LDS.
// P-1: stage hB(bf16) + WT_h (in S region) + edges. P0: qkv = hB@WT_h^T via MFMA
// (bias C-init; q/k->LDS bf16, v->regs, r8/qb->LDS fp32). P1..P5 as before.
__global__ void __launch_bounds__(1024, 4) k_attn(const float* __restrict__ hbuf,
                                                  const unsigned short* __restrict__ WcatT,
                                                  const float* __restrict__ bcatT,
                                                  float* __restrict__ abuf,
                                                  const float* __restrict__ edge_attr,
                                                  const int* __restrict__ ei) {
  __shared__ unsigned short Qu[128 * QS];   // Q bf16
  __shared__ unsigned short KVu[128 * QS];  // P0-P1: K; P2+: Vt (64 x stride VS)
  __shared__ float S[128 * SP];             // P-1..P0: hB(20KB)+WT(26.6KB); P1+: scores/Wmat
  __shared__ float alphaL[EPG];
  __shared__ int edL[EPG];                  // src | dst<<16
  __shared__ float r8L[128 * 8];
  __shared__ float t8L[128 * 9];
  __shared__ unsigned mL[128];
  __shared__ float sL[128], qbL[128];
  int g = blockIdx.x, h = blockIdx.y;
  int tid = threadIdx.x;
  int lane = tid & 63, m16 = lane & 15, quad = lane >> 4, wv = tid >> 6;
  float* aF = abuf + (size_t)g * 128 * ASF;
  const float* eaG = edge_attr + (size_t)g * EPG * 8;
  unsigned short* hB = (unsigned short*)S;          // 128 x QS hw = 20480 B
  unsigned short* WT = hB + 128 * QS;               // WC x 64 hw = 26624 B (total 47104 < 67584)
  const float* bcT = bcatT + (blockIdx.y + 0) * 0;  // silence unused warn pattern

  // ---- P-1: stage hB (fp32->bf16), WT_h, edges; zero m/s/t8
  {
    int n8 = tid >> 3, c8 = tid & 7;
    const float* hr = hbuf + (size_t)g * 8192 + n8 * 64 + c8 * 8;
    float4 a0 = *(const float4*)(hr), a1 = *(const float4*)(hr + 4);
    uint4 hp;
    hp.x = f2bf(a0.x) | ((unsigned)f2bf(a0.y) << 16);
    hp.y = f2bf(a0.z) | ((unsigned)f2bf(a0.w) << 16);
    hp.z = f2bf(a1.x) | ((unsigned)f2bf(a1.y) << 16);
    hp.w = f2bf(a1.z) | ((unsigned)f2bf(a1.w) << 16);
    *(uint4*)&hB[n8 * QS + c8 * 8] = hp;
  }
  {
    const unsigned short* WTg = WcatT + (size_t)(blockIdx.y + 4 * 0 + (0)) * 0;  // placeholder
    const unsigned short* src = WcatT;  // real addressing below
    (void)WTg; (void)src;
  }
  {
    int lh = /*layer folded into pointer*/ h;  // WcatT passed pre-offset to layer; add head
    const uint4* wsrc = (const uint4*)(WcatT + (size_t)lh * WC * 64);
    for (int idx = tid; idx < WC * 64 / 8; idx += 1024)  // 1664 uint4
      *(uint4*)&WT[idx * 8] = wsrc[idx];
  }
  if (tid < 128) {
    mL[tid] = 0u;
    sL[tid] = 0.f;
  }
  for (int idx = tid; idx < EPG; idx += 1024) {
    t8L[idx] = 0.f;  // EPG == 128*9
    int s = ei[g * EPG + idx] - g * 128;
    int d = ei[Ej + g * EPG + idx] - g * 128;
    edL[idx] = s | (d << 16);
  }
  __syncthreads();

  // ---- P0: fused GEMM out[node][col] = hB @ WT^T + bias. 104 tiles (8 m-strips x 13 n-tiles).
  f32x4 vfrag[2];
  int vm[2], vc[2], vcount = 0;
  const float* bcTl = bcatT + (size_t)h * WC;  // bcatT passed pre-offset to layer
  for (int t = wv; t < 104; t += 16) {
    int m0 = (t & 7) * 16, n0 = (t >> 3) * 16;
    const short8 a0 = *(const short8*)&hB[(m0 + m16) * QS + quad * 8];
    const short8 a1 = *(const short8*)&hB[(m0 + m16) * QS + 32 + quad * 8];
    const short8 b0 = *(const short8*)&WT[(n0 + m16) * 64 + quad * 8];
    const short8 b1 = *(const short8*)&WT[(n0 + m16) * 64 + 32 + quad * 8];
    float bias = bcTl[n0 + m16];
    f32x4 acc = {bias, bias, bias, bias};
    acc = __builtin_amdgcn_mfma_f32_16x16x32_bf16(a0, b0, acc, 0, 0, 0);
    acc = __builtin_amdgcn_mfma_f32_16x16x32_bf16(a1, b1, acc, 0, 0, 0);
    if (n0 < 64) {
#pragma unroll
      for (int r = 0; r < 4; ++r)
        Qu[(m0 + quad * 4 + r) * QS + n0 + m16] = f2bf(acc[r]);
    } else if (n0 < 128) {
#pragma unroll
      for (int r = 0; r < 4; ++r)
        KVu[(m0 + quad * 4 + r) * QS + (n0 - 64) + m16] = f2bf(acc[r]);
    } else if (n0 < 192) {
      vfrag[vcount] = acc; vm[vcount] = m0; vc[vcount] = n0 - 128; ++vcount;
    } else {
      if (m16 < 8) {
#pragma unroll
        for (int r = 0; r < 4; ++r)
          r8L[(m0 + quad * 4 + r) * 8 + m16] = acc[r];
      } else if (m16 == 8) {
#pragma unroll
        for (int r = 0; r < 4; ++r)
          qbL[m0 + quad * 4 + r] = acc[r];
      }
    }
  }
  __syncthreads();

  // ---- P1: S = Q@K^T. 2 waves per dst strip; 4 src tiles each.
  {
    int strip = wv >> 1, halfw = wv & 1;
    int dst0 = strip * 16;
    const short8 a0 = *(const short8*)&Qu[(dst0 + m16) * QS + quad * 8];
    const short8 a1 = *(const short8*)&Qu[(dst0 + m16) * QS + 32 + quad * 8];
#pragma unroll
    for (int t = 0; t < 4; ++t) {
      int src0 = (halfw * 4 + t) * 16;
      const short8 b0 = *(const short8*)&KVu[(src0 + m16) * QS + quad * 8];
      const short8 b1 = *(const short8*)&KVu[(src0 + m16) * QS + 32 + quad * 8];
      f32x4 acc = {0.f, 0.f, 0.f, 0.f};
      acc = __builtin_amdgcn_mfma_f32_16x16x32_bf16(a0, b0, acc, 0, 0, 0);
      acc = __builtin_amdgcn_mfma_f32_16x16x32_bf16(a1, b1, acc, 0, 0, 0);
#pragma unroll
      for (int r = 0; r < 4; ++r)
        S[(dst0 + quad * 4 + r) * SP + src0 + m16] = acc[r];
    }
  }
  __syncthreads();

  // ---- P2: deposit v frags -> Vt (bf16, transposed); per-edge alpha; segment max
#pragma unroll
  for (int i = 0; i < 2; ++i) {
    int col = vc[i] + m16;
#pragma unroll
    for (int r = 0; r < 4; ++r)
      KVu[col * VS + vm[i] + quad * 4 + r] = f2bf(vfrag[i][r]);
  }
  for (int e = tid; e < EPG; e += 1024) {
    int ed = edL[e];
    int src = ed & 0xffff, dst = ed >> 16;
    float4 ea0 = *(const float4*)(eaG + (size_t)e * 8);
    float4 ea1 = *(const float4*)(eaG + (size_t)e * 8 + 4);
    float4 r80 = *(const float4*)&r8L[dst * 8];
    float4 r81 = *(const float4*)&r8L[dst * 8 + 4];
    float a = S[dst * SP + src] + qbL[dst]
            + ea0.x * r80.x + ea0.y * r80.y + ea0.z * r80.z + ea0.w * r80.w
            + ea1.x * r81.x + ea1.y * r81.y + ea1.z * r81.z + ea1.w * r81.w;
    alphaL[e] = a;
    atomicMax(&mL[dst], encf(a));
  }
  __syncthreads();

  // ---- P3: zero S; exp + segment sum
  for (int idx = tid; idx < 128 * (SP / 4); idx += 1024)
    *(float4*)&S[idx * 4] = make_float4(0.f, 0.f, 0.f, 0.f);
  for (int e = tid; e < EPG; e += 1024) {
    int dst = edL[e] >> 16;
    float ex = expf(alphaL[e] - decf(mL[dst]));
    alphaL[e] = ex;
    atomicAdd(&sL[dst], ex);
  }
  __syncthreads();

  // ---- P4: scatter normalized weights into Wmat(fp32); accumulate t8
  for (int e = tid; e < EPG; e += 1024) {
    int ed = edL[e];
    int src = ed & 0xffff, dst = ed >> 16;
    float w = alphaL[e] / fmaxf(sL[dst], 1e-16f);
    atomicAdd(&S[dst * SP + src], w);
    float4 ea0 = *(const float4*)(eaG + (size_t)e * 8);
    float4 ea1 = *(const float4*)(eaG + (size_t)e * 8 + 4);
    float* t8 = &t8L[dst * 9];
    atomicAdd(t8 + 0, w * ea0.x); atomicAdd(t8 + 1, w * ea0.y);
    atomicAdd(t8 + 2, w * ea0.z); atomicAdd(t8 + 3, w * ea0.w);
    atomicAdd(t8 + 4, w * ea1.x); atomicAdd(t8 + 5, w * ea1.y);
    atomicAdd(t8 + 6, w * ea1.z); atomicAdd(t8 + 7, w * ea1.w);
  }
  __syncthreads();

  // ---- P4.5: repack Wmat fp32 -> bf16 in place (stride VS)
  {
    float vals[16];
    int i0 = tid * 16;
    int dst = i0 >> 7, src0 = i0 & 127;
#pragma unroll
    for (int i = 0; i < 16; ++i)
      vals[i] = S[dst * SP + src0 + i];
    __syncthreads();
    unsigned short* Wu = (unsigned short*)S;
#pragma unroll
    for (int g4 = 0; g4 < 2; ++g4) {
      uint4 u;
      u.x = f2bf(vals[g4 * 8 + 0]) | ((unsigned)f2bf(vals[g4 * 8 + 1]) << 16);
      u.y = f2bf(vals[g4 * 8 + 2]) | ((unsigned)f2bf(vals[g4 * 8 + 3]) << 16);
      u.z = f2bf(vals[g4 * 8 + 4]) | ((unsigned)f2bf(vals[g4 * 8 + 5]) << 16);
      u.w = f2bf(vals[g4 * 8 + 6]) | ((unsigned)f2bf(vals[g4 * 8 + 7]) << 16);
      *(uint4*)&Wu[dst * VS + src0 + g4 * 8] = u;
    }
  }
  __syncthreads();

  // ---- P5: agg = Wmat(128x128)@V(128x64) via MFMA -> abuf
  {
    const unsigned short* Wu = (const unsigned short*)S;
    int strip = wv >> 1, halfc = wv & 1;
    int dst0 = strip * 16;
    short8 a[4];
#pragma unroll
    for (int ks = 0; ks < 4; ++ks)
      a[ks] = *(const short8*)&Wu[(dst0 + m16) * VS + ks * 32 + quad * 8];
#pragma unroll
    for (int t = 0; t < 2; ++t) {
      int c0 = (halfc * 2 + t) * 16;
      f32x4 acc = {0.f, 0.f, 0.f, 0.f};
#pragma unroll
      for (int ks = 0; ks < 4; ++ks) {
        const short8 b = *(const short8*)&KVu[(c0 + m16) * VS + ks * 32 + quad * 8];
        acc = __builtin_amdgcn_mfma_f32_16x16x32_bf16(a[ks], b, acc, 0, 0, 0);
      }
#pragma unroll
      for (int r = 0; r < 4; ++r)
        aF[(size_t)(dst0 + quad * 4 + r) * ASF + h * 64 + c0 + m16] = acc[r];
    }
  }
  // t8 + s writeback
  if (tid < 128) {
    float tmp[8];
#pragma unroll
    for (int j = 0; j < 8; ++j) tmp[j] = t8L[tid * 9 + j];
    *(float4*)(aF + (size_t)tid * ASF + 256 + h * 8) = make_float4(tmp[0], tmp[1], tmp[2], tmp[3]);
    *(float4*)(aF + (size_t)tid * ASF + 256 + h * 8 + 4) = make_float4(tmp[4], tmp[5], tmp[6], tmp[7]);
    aF[(size_t)tid * ASF + 288 + h] = sL[tid];
  }
}

// out[n,c] = 0.25*sum_h( agg + t8@G_h + (s>0)*bb_h ) + h@Wskip+bskip; vemb; h += out
__global__ void __launch_bounds__(256) k_update(float* h, const float* __restrict__ abuf,
                                                const float* __restrict__ Wskip_l,
                                                const float* __restrict__ bskip_l,
                                                const float* __restrict__ G_l,
                                                const float* __restrict__ bb_l,
                                                float* __restrict__ vemb, int layer) {
  __shared__ float h4[256];
  int n0 = blockIdx.x * 4;
  h4[threadIdx.x] = h[(size_t)n0 * 64 + threadIdx.x];
  __syncthreads();
  int nn = threadIdx.x >> 6, c = threadIdx.x & 63;
  int n = n0 + nn;
  const float* hr = &h4[nn * 64];
  float sk = bskip_l[c];
#pragma unroll 8
  for (int d = 0; d < 64; ++d)
    sk += hr[d] * Wskip_l[d * 64 + c];
  const float* rowA = abuf + (size_t)n * ASF;
  float acc = 0.f;
#pragma unroll
  for (int hh = 0; hh < 4; ++hh) {
    float sw = (rowA[288 + hh] > 0.f) ? 1.f : 0.f;
    float a = rowA[hh * 64 + c] + sw * bb_l[hh * 64 + c];
#pragma unroll
    for (int a8 = 0; a8 < 8; ++a8)
      a += rowA[256 + hh * 8 + a8] * G_l[(hh * 8 + a8) * 64 + c];
    acc += a;
  }
  float outv = acc * 0.25f + sk;
  if ((n & 127) == 127)
    vemb[(n >> 7) * 256 + layer * 64 + c] = outv;
  h[(size_t)n * 64 + c] = outv + hr[c];
}

// pool = vemb @ W_down + b_down; out = sigmoid(pool @ W_out + b_out)
__global__ void k_head(const float* __restrict__ vemb, const float* __restrict__ Wd,
                       const float* __restrict__ bd, const float* __restrict__ Wo,
                       const float* __restrict__ bo, float* __restrict__ out) {
  int g = blockIdx.x;
  int c = threadIdx.x;  // 64 threads
  const float* vr = vemb + g * 256;
  float acc = bd[c];
#pragma unroll 16
  for (int j = 0; j < 256; ++j)
    acc += vr[j] * Wd[j * 64 + c];
  float p = acc * Wo[c];
#pragma unroll
  for (int off = 32; off; off >>= 1) p += __shfl_down(p, off);
  if (c == 0) {
    float logit = p + bo[0];
    out[g] = 1.f / (1.f + expf(-logit));
  }
}

extern "C" void kernel_launch(void* const* d_in, const int* in_sizes, int n_in,
                              void* d_out, int out_size, void* d_ws, size_t ws_size,
                              hipStream_t stream) {
  const float* x         = (const float*)d_in[0];
  const float* edge_attr = (const float*)d_in[1];
  const int*   ei        = (const int*)d_in[2];
  const float* W_node = (const float*)d_in[4];
  const float* b_node = (const float*)d_in[5];
  const float* W_edge = (const float*)d_in[6];
  const float* b_edge = (const float*)d_in[7];
  const float* Wq = (const float*)d_in[8];
  const float* bq = (const float*)d_in[9];
  const float* Wk = (const float*)d_in[10];
  const float* bk = (const float*)d_in[11];
  const float* Wv = (const float*)d_in[12];
  const float* bv = (const float*)d_in[13];
  const float* We = (const float*)d_in[14];
  const float* be = (const float*)d_in[15];
  const float* Wskip = (const float*)d_in[16];
  const float* bskip = (const float*)d_in[17];
  const float* W_down = (const float*)d_in[18];
  const float* b_down = (const float*)d_in[19];
  const float* W_out  = (const float*)d_in[20];
  const float* b_out  = (const float*)d_in[21];
  float* out = (float*)d_out;

  // workspace carve: ~49 MB
  float* p = (float*)d_ws;
  float* hbuf  = p; p += (size_t)Nn * 64;        //  8.4 MB
  float* abuf  = p; p += (size_t)Nn * ASF;       // 39.8 MB
  unsigned short* WcatT = (unsigned short*)p; p += (size_t)4 * 4 * WC * 64 / 2;  // bf16
  float* bcatT = p; p += (size_t)4 * 4 * WC;
  float* Gbuf  = p; p += (size_t)4 * 4 * 8 * 64;
  float* bbuf  = p; p += (size_t)4 * 4 * 64;
  float* vemb  = p; p += (size_t)Bg * 256;

  k_prep2<<<36, 256, 0, stream>>>(We, be, W_edge, b_edge, Gbuf, bbuf);
  k_prepT_light<<<(4 * 4 * WC * 64 + 255) / 256, 256, 0, stream>>>(Wq, bq, Wk, bk, Wv, bv,
                                                                   WcatT, bcatT);
  k_prepT_heavy<<<2304, 256, 0, stream>>>(Wq, bq, We, be, W_edge, b_edge, WcatT, bcatT);
  k_node_enc<<<Nn * 64 / 256, 256, 0, stream>>>(x, W_node, b_node, hbuf);

  for (int i = 0; i < 4; ++i) {
    k_attn<<<dim3(Bg, 4), 1024, 0, stream>>>(hbuf, WcatT + (size_t)i * 4 * WC * 64,
                                             bcatT + (size_t)i * 4 * WC, abuf, edge_attr, ei);
    k_update<<<Nn / 4, 256, 0, stream>>>(hbuf, abuf, Wskip + i * 4096, bskip + i * 64,
                                         Gbuf + i * 2048, bbuf + i * 256, vemb, i);
  }
  k_head<<<Bg, 64, 0, stream>>>(vemb, W_down, b_down, W_out, b_out, out);
}